// Round 5
// baseline (258.781 us; speedup 1.0000x reference)
//
#include <hip/hip_runtime.h>

typedef __fp16   pk16x2 __attribute__((ext_vector_type(2)));
typedef _Float16 f16x8 __attribute__((ext_vector_type(8)));
typedef float    f32x16 __attribute__((ext_vector_type(16)));

static constexpr int BSZ = 32768;
static constexpr int NB  = 8;
static constexpr int NW  = 256;
static constexpr int LW  = 64;
static constexpr int DF  = 512;
#define TAU   5.0f
#define LOG2E 1.44269504088896f
#define LN2   0.69314718055994f

union U2 { pk16x2 h; unsigned u; };
union U8 { f16x8 v; unsigned u[4]; };
union F4 { float4 v; float a[4]; };

__device__ inline unsigned pku(float a, float b) {
    U2 c; c.h = __builtin_amdgcn_cvt_pkrtz(a, b); return c.u;
}

// ws layout (bytes): cbh fp16 [k][w][l] @0 (256K) | cbt fp16 [k][l][w] @256K (256K)
// | cc f32 [k][w] @512K (8K) | w1h fp16 [h][l] @520K (32K) | w2h fp16 [8][256] @552K (4K)
static constexpr size_t WS_CBH = 0;
static constexpr size_t WS_CBT = 262144;
static constexpr size_t WS_CC  = 524288;
static constexpr size_t WS_W1H = 532480;
static constexpr size_t WS_W2H = 565248;

// ---------------------------------------------------------------------------
// Prep: one-time fp32->fp16 conversion + transposes + ||c||^2. 9 blocks.
// ---------------------------------------------------------------------------
__global__ __launch_bounds__(256) void prep_kernel(
    const float* __restrict__ cb, const float* __restrict__ W1,
    const float* __restrict__ W2, char* __restrict__ ws)
{
    _Float16* cbh = (_Float16*)(ws + WS_CBH);
    _Float16* cbt = (_Float16*)(ws + WS_CBT);
    float*    cc  = (float*)   (ws + WS_CC);
    _Float16* w1h = (_Float16*)(ws + WS_W1H);
    _Float16* w2h = (_Float16*)(ws + WS_W2H);
    const int b = blockIdx.x, t = threadIdx.x;

    if (b < 8) {
        // word w = t of book b
        const float* src = cb + (size_t)t * DF + b * LW;
        float c_[64];
        #pragma unroll
        for (int i = 0; i < 16; ++i)
            *(float4*)&c_[i * 4] = *(const float4*)(src + i * 4);
        float s = 0.f;
        #pragma unroll
        for (int l = 0; l < 64; ++l) s += c_[l] * c_[l];
        cc[b * 256 + t] = s;
        #pragma unroll
        for (int c8 = 0; c8 < 8; ++c8) {
            U8 u;
            #pragma unroll
            for (int m = 0; m < 4; ++m)
                u.u[m] = pku(c_[c8 * 8 + 2 * m], c_[c8 * 8 + 2 * m + 1]);
            *(f16x8*)&cbh[((size_t)(b * 256 + t)) * 64 + c8 * 8] = u.v;
        }
        #pragma unroll
        for (int l = 0; l < 64; ++l)
            cbt[((size_t)(b * 64 + l)) * 256 + t] = (_Float16)c_[l];
    } else {
        // W1^T: w1h[h=t][l]
        float wv[64];
        #pragma unroll
        for (int l = 0; l < 64; ++l) wv[l] = W1[l * 256 + t];
        #pragma unroll
        for (int c8 = 0; c8 < 8; ++c8) {
            U8 u;
            #pragma unroll
            for (int m = 0; m < 4; ++m)
                u.u[m] = pku(wv[c8 * 8 + 2 * m], wv[c8 * 8 + 2 * m + 1]);
            *(f16x8*)&w1h[(size_t)t * 64 + c8 * 8] = u.v;
        }
        // W2^T: w2h[c][h], c = t>>5, 8 h per thread
        const int c = t >> 5, h0 = (t & 31) * 8;
        #pragma unroll
        for (int j = 0; j < 8; ++j)
            w2h[c * 256 + h0 + j] = (_Float16)W2[(h0 + j) * 8 + c];
    }
}

// ---------------------------------------------------------------------------
// Fused kernel: grid (BSZ/128, NB), block 256 (4 waves), ZERO LDS, no barriers.
// Each wave: 32 rows of one book. dist GEMM (A=cbh global, swapped) ->
// in-register softmax -> z GEMM + p store -> MLP G1 (A=w1h) -> G2 (A=w2h)
// -> log_softmax. All A-operands from global (L1/L2-resident fp16).
// Lane32-exchange via proven shfl_xor+cndmask (permlane asm miscompiled, R4).
// ---------------------------------------------------------------------------
__global__ __launch_bounds__(256, 2) void fused_kernel(
    const float* __restrict__ f, const char* __restrict__ ws,
    const float* __restrict__ b1, const float* __restrict__ b2,
    float* __restrict__ out_f, float* __restrict__ out_z,
    float* __restrict__ out_p, float* __restrict__ out_lg)
{
    const _Float16* cbh = (const _Float16*)(ws + WS_CBH);
    const _Float16* cbt = (const _Float16*)(ws + WS_CBT);
    const float*    cc  = (const float*)   (ws + WS_CC);
    const _Float16* w1h = (const _Float16*)(ws + WS_W1H);
    const _Float16* w2h = (const _Float16*)(ws + WS_W2H);

    const int k    = blockIdx.y;
    const int tid  = threadIdx.x;
    const int wid  = tid >> 6;
    const int lane = tid & 63;
    const int lr   = lane & 31;
    const int hi   = lane >> 5;
    const int row  = blockIdx.x * 128 + wid * 32 + lr;

    // ---- x load (+ fused out_f passthrough): covers f[row][k*64 .. +64) ----
    float x_[32];
    {
        const float* fr = f     + (size_t)row * DF + k * LW + hi * 8;
        float*       fo = out_f + (size_t)row * DF + k * LW + hi * 8;
        #pragma unroll
        for (int i = 0; i < 8; ++i) {
            float4 v = *(const float4*)(fr + (i >> 1) * 16 + (i & 1) * 4);
            *(float4*)&x_[i * 4] = v;
            *(float4*)(fo + (i >> 1) * 16 + (i & 1) * 4) = v;
        }
    }

    // ---- x -> fp16 hi/lo split fragments (B-operand, k=l slices) ----
    f16x8 bxh[4], bxl[4];
    #pragma unroll
    for (int ks = 0; ks < 4; ++ks) {
        U8 uh, ul;
        #pragma unroll
        for (int m = 0; m < 4; ++m) {
            float a = x_[ks * 8 + 2 * m], b = x_[ks * 8 + 2 * m + 1];
            pk16x2 ph = __builtin_amdgcn_cvt_pkrtz(a, b);
            U2 c; c.h = ph;
            uh.u[m] = c.u;
            ul.u[m] = pku(a - (float)ph[0], b - (float)ph[1]);
        }
        bxh[ks] = uh.v; bxl[ks] = ul.v;
    }

    // ---- distance GEMM: acc[wt][q] = dot(c_w, x_row), A from global ----
    const _Float16* ca = cbh + (size_t)k * NW * LW;
    f32x16 acc[8];
    #pragma unroll
    for (int wt = 0; wt < 8; ++wt) acc[wt] = {};
    #pragma unroll
    for (int wt = 0; wt < 8; ++wt) {
        #pragma unroll
        for (int ks = 0; ks < 4; ++ks) {
            f16x8 a = *(const f16x8*)(ca + (size_t)(wt * 32 + lr) * 64 + ks * 16 + hi * 8);
            acc[wt] = __builtin_amdgcn_mfma_f32_32x32x16_f16(a, bxh[ks], acc[wt], 0, 0, 0);
            acc[wt] = __builtin_amdgcn_mfma_f32_32x32x16_f16(a, bxl[ks], acc[wt], 0, 0, 0);
        }
    }

    // ---- softmax over 256 w (exp2 domain); logit = (2*dot - cc)*TAU*log2e ----
    const float* ccb = cc + k * NW;
    const float KK = TAU * LOG2E;
    float mx = -1e30f;
    #pragma unroll
    for (int wt = 0; wt < 8; ++wt) {
        #pragma unroll
        for (int g = 0; g < 4; ++g) {
            F4 cc4; cc4.v = *(const float4*)&ccb[wt * 32 + g * 8 + hi * 4];
            #pragma unroll
            for (int j = 0; j < 4; ++j) {
                int q = g * 4 + j;
                float li = (2.f * acc[wt][q] - cc4.a[j]) * KK;
                acc[wt][q] = li;
                mx = fmaxf(mx, li);
            }
        }
    }
    mx = fmaxf(mx, __shfl_xor(mx, 32));
    float s = 0.f;
    #pragma unroll
    for (int wt = 0; wt < 8; ++wt) {
        #pragma unroll
        for (int q = 0; q < 16; ++q) {
            float e = __builtin_amdgcn_exp2f(acc[wt][q] - mx);
            acc[wt][q] = e; s += e;
        }
    }
    s += __shfl_xor(s, 32);
    const float inv = 1.f / s;
    #pragma unroll
    for (int wt = 0; wt < 8; ++wt) {
        #pragma unroll
        for (int q = 0; q < 16; ++q) acc[wt][q] *= inv;
    }

    // ---- z GEMM + p writeback (A=P via shfl_xor exchange, B=cbt global) ----
    float* prow = out_p + (size_t)row * (NB * NW) + (size_t)k * NW + hi * 8;
    const _Float16* cz = cbt + (size_t)k * LW * NW;
    f32x16 zacc[2];
    zacc[0] = {}; zacc[1] = {};
    #pragma unroll
    for (int ks = 0; ks < 16; ++ks) {
        const int wt = ks >> 1;
        const int q0 = (ks & 1) * 8;
        float v[8];
        #pragma unroll
        for (int i = 0; i < 4; ++i) {
            float a0 = acc[wt][q0 + i];
            float a1 = acc[wt][q0 + 4 + i];
            float snd = hi ? a0 : a1;
            float rcv = __shfl_xor(snd, 32);
            v[i]     = hi ? rcv : a0;
            v[4 + i] = hi ? a1 : rcv;
        }
        *(float4*)(prow + ks * 16)     = float4{v[0], v[1], v[2], v[3]};
        *(float4*)(prow + ks * 16 + 4) = float4{v[4], v[5], v[6], v[7]};
        U8 pa;
        pa.u[0] = pku(v[0], v[1]); pa.u[1] = pku(v[2], v[3]);
        pa.u[2] = pku(v[4], v[5]); pa.u[3] = pku(v[6], v[7]);
        #pragma unroll
        for (int nt = 0; nt < 2; ++nt) {
            f16x8 bz = *(const f16x8*)(cz + (size_t)(nt * 32 + lr) * 256 + ks * 16 + hi * 8);
            zacc[nt] = __builtin_amdgcn_mfma_f32_32x32x16_f16(pa.v, bz, zacc[nt], 0, 0, 0);
        }
    }
    const int rbase = blockIdx.x * 128 + wid * 32;
    #pragma unroll
    for (int nt = 0; nt < 2; ++nt) {
        #pragma unroll
        for (int q = 0; q < 16; ++q) {
            int rr = (q & 3) + 8 * (q >> 2) + 4 * hi;
            out_z[(size_t)(rbase + rr) * DF + k * LW + nt * 32 + lr] = zacc[nt][q];
        }
    }

    // ---- MLP G1: h = relu(x @ W1 + b1); A=w1h global, B=bxh ----
    f32x16 acc1[8];
    #pragma unroll
    for (int ht = 0; ht < 8; ++ht) acc1[ht] = {};
    #pragma unroll
    for (int ht = 0; ht < 8; ++ht) {
        #pragma unroll
        for (int ks = 0; ks < 4; ++ks) {
            f16x8 a = *(const f16x8*)(w1h + (size_t)(ht * 32 + lr) * 64 + ks * 16 + hi * 8);
            acc1[ht] = __builtin_amdgcn_mfma_f32_32x32x16_f16(a, bxh[ks], acc1[ht], 0, 0, 0);
        }
    }
    #pragma unroll
    for (int ht = 0; ht < 8; ++ht) {
        #pragma unroll
        for (int g = 0; g < 4; ++g) {
            F4 b4; b4.v = *(const float4*)&b1[ht * 32 + g * 8 + hi * 4];
            #pragma unroll
            for (int j = 0; j < 4; ++j) {
                int q = g * 4 + j;
                acc1[ht][q] = fmaxf(acc1[ht][q] + b4.a[j], 0.f);
            }
        }
    }

    // ---- G2: logits = h @ W2 + b2 (A rows = classes, replicated over lr&7) ----
    f32x16 acc2 = {};
    #pragma unroll
    for (int ks = 0; ks < 16; ++ks) {
        const int ht = ks >> 1;
        const int q0 = (ks & 1) * 8;
        float v[8];
        #pragma unroll
        for (int i = 0; i < 4; ++i) {
            float a0 = acc1[ht][q0 + i];
            float a1 = acc1[ht][q0 + 4 + i];
            float snd = hi ? a0 : a1;
            float rcv = __shfl_xor(snd, 32);
            v[i]     = hi ? rcv : a0;
            v[4 + i] = hi ? a1 : rcv;
        }
        U8 hb;
        hb.u[0] = pku(v[0], v[1]); hb.u[1] = pku(v[2], v[3]);
        hb.u[2] = pku(v[4], v[5]); hb.u[3] = pku(v[6], v[7]);
        f16x8 aw2 = *(const f16x8*)(w2h + (size_t)(lr & 7) * 256 + ks * 16 + hi * 8);
        acc2 = __builtin_amdgcn_mfma_f32_32x32x16_f16(aw2, hb.v, acc2, 0, 0, 0);
    }

    // ---- log_softmax over 8 classes: regs q=0..3 hold classes q + 4*hi ----
    F4 b2v; b2v.v = *(const float4*)&b2[hi * 4];
    float lg[4];
    #pragma unroll
    for (int q = 0; q < 4; ++q) lg[q] = acc2[q] + b2v.a[q];
    float m = fmaxf(fmaxf(lg[0], lg[1]), fmaxf(lg[2], lg[3]));
    m = fmaxf(m, __shfl_xor(m, 32));
    float se = 0.f;
    #pragma unroll
    for (int q = 0; q < 4; ++q) se += __builtin_amdgcn_exp2f((lg[q] - m) * LOG2E);
    se += __shfl_xor(se, 32);
    float lse = m + __builtin_amdgcn_logf(se) * LN2;
    *(float4*)(out_lg + (size_t)row * 64 + k * 8 + hi * 4) =
        float4{lg[0] - lse, lg[1] - lse, lg[2] - lse, lg[3] - lse};
}

extern "C" void kernel_launch(void* const* d_in, const int* in_sizes, int n_in,
                              void* d_out, int out_size, void* d_ws, size_t ws_size,
                              hipStream_t stream) {
    const float* f  = (const float*)d_in[0];
    const float* cb = (const float*)d_in[1];
    const float* W1 = (const float*)d_in[2];
    const float* b1 = (const float*)d_in[3];
    const float* W2 = (const float*)d_in[4];
    const float* b2 = (const float*)d_in[5];

    float* out    = (float*)d_out;
    float* out_f  = out;
    float* out_z  = out_f + (size_t)BSZ * DF;
    float* out_p  = out_z + (size_t)BSZ * DF;
    float* out_lg = out_p + (size_t)BSZ * NB * NW;

    hipLaunchKernelGGL(prep_kernel, dim3(9), dim3(256), 0, stream,
                       cb, W1, W2, (char*)d_ws);
    hipLaunchKernelGGL(fused_kernel, dim3(BSZ / 128, NB), dim3(256), 0, stream,
                       f, (const char*)d_ws, b1, b2, out_f, out_z, out_p, out_lg);
}